// Round 1
// baseline (962.692 us; speedup 1.0000x reference)
//
#include <hip/hip_runtime.h>
#include <hip/hip_bf16.h>
#include <math.h>

#define N_NODES 50000
#define N_EDGES 600000
#define D_IN    44

// ---------------- degree / norm ----------------

__global__ void k_deg_init(float* deg, int n) {
    int i = blockIdx.x * blockDim.x + threadIdx.x;
    if (i < n) deg[i] = 1.0f;   // self-loop contribution
}

__global__ void k_deg_acc(const int* __restrict__ dst, float* deg, int e) {
    int i = blockIdx.x * blockDim.x + threadIdx.x;
    if (i < e) atomicAdd(&deg[dst[i]], 1.0f);
}

__global__ void k_dinv(float* deg, int n) {
    int i = blockIdx.x * blockDim.x + threadIdx.x;
    if (i < n) deg[i] = rsqrtf(fmaxf(deg[i], 1.0f));   // in-place -> dinv
}

// ---------------- dense GEMM: H[n,DO] = act(X[n,DI]) @ W[DI,DO] ----------------
// W staged in LDS. block = 256 threads = (256/DO) nodes x DO columns.

template<int DI, int DO, bool RELU_IN>
__global__ void k_gemm(const float* __restrict__ X, const float* __restrict__ W,
                       float* __restrict__ H, int n) {
    __shared__ float Ws[DI * DO];
    for (int i = threadIdx.x; i < DI * DO; i += blockDim.x) Ws[i] = W[i];
    __syncthreads();

    const int npb   = 256 / DO;                 // nodes per block
    const int j     = threadIdx.x % DO;
    const int local = threadIdx.x / DO;

    for (int node = blockIdx.x * npb + local; node < n; node += gridDim.x * npb) {
        const float* xr = X + (size_t)node * DI;
        float acc = 0.0f;
        #pragma unroll
        for (int k = 0; k < DI; ++k) {
            float xv = xr[k];
            if (RELU_IN) xv = fmaxf(xv, 0.0f);
            acc += xv * Ws[k * DO + j];
        }
        H[(size_t)node * DO + j] = acc;
    }
}

// ---------------- O[i,j] = H[i,j]*dinv[i]^2 + b[j]  (self loop + bias) ----------------

template<int DO>
__global__ void k_init_out(const float* __restrict__ H, const float* __restrict__ dinv,
                           const float* __restrict__ b, float* __restrict__ O, int n) {
    int idx = blockIdx.x * blockDim.x + threadIdx.x;
    int total = n * DO;
    if (idx < total) {
        int node = idx / DO;
        int j    = idx % DO;
        float di = dinv[node];
        O[idx] = H[idx] * di * di + b[j];
    }
}

// ---------------- edge scatter: O[dst,j] += dinv[src]*dinv[dst]*H[src,j] ----------------

template<int DO>
__global__ void k_scatter(const float* __restrict__ H, const float* __restrict__ dinv,
                          const int* __restrict__ src, const int* __restrict__ dst,
                          float* __restrict__ O, int e) {
    int idx = blockIdx.x * blockDim.x + threadIdx.x;
    int total = e * DO;
    if (idx < total) {
        int ed = idx / DO;
        int j  = idx % DO;
        int s = src[ed];
        int d = dst[ed];
        float nrm = dinv[s] * dinv[d];
        atomicAdd(&O[d * DO + j], H[s * DO + j] * nrm);
    }
}

// ---------------- MLP head: relu(O3) -> 16 relu -> 1 sigmoid ----------------

__global__ void k_mlp(const float* __restrict__ O3,
                      const float* __restrict__ Wf1, const float* __restrict__ bf1,
                      const float* __restrict__ Wf2, const float* __restrict__ bf2,
                      float* __restrict__ out, int n) {
    __shared__ float W1s[32 * 16];
    __shared__ float b1s[16];
    __shared__ float W2s[16];
    __shared__ float b2s;
    for (int t = threadIdx.x; t < 32 * 16; t += blockDim.x) W1s[t] = Wf1[t];
    if (threadIdx.x < 16) { b1s[threadIdx.x] = bf1[threadIdx.x]; W2s[threadIdx.x] = Wf2[threadIdx.x]; }
    if (threadIdx.x == 0) b2s = bf2[0];
    __syncthreads();

    for (int node = blockIdx.x * blockDim.x + threadIdx.x; node < n;
         node += gridDim.x * blockDim.x) {
        float h[16];
        #pragma unroll
        for (int j = 0; j < 16; ++j) h[j] = b1s[j];
        const float* xr = O3 + (size_t)node * 32;
        #pragma unroll
        for (int k = 0; k < 32; ++k) {
            float xv = fmaxf(xr[k], 0.0f);
            #pragma unroll
            for (int j = 0; j < 16; ++j) h[j] += xv * W1s[k * 16 + j];
        }
        float acc = b2s;
        #pragma unroll
        for (int j = 0; j < 16; ++j) acc += fmaxf(h[j], 0.0f) * W2s[j];
        out[node] = 1.0f / (1.0f + expf(-acc));
    }
}

// ---------------- launch ----------------

extern "C" void kernel_launch(void* const* d_in, const int* in_sizes, int n_in,
                              void* d_out, int out_size, void* d_ws, size_t ws_size,
                              hipStream_t stream) {
    const float* x   = (const float*)d_in[0];
    const int*   ei  = (const int*)d_in[1];   // [2, E]: src then dst
    const float* W1  = (const float*)d_in[2];
    const float* b1  = (const float*)d_in[3];
    const float* W2  = (const float*)d_in[4];
    const float* b2  = (const float*)d_in[5];
    const float* W3  = (const float*)d_in[6];
    const float* b3  = (const float*)d_in[7];
    const float* Wf1 = (const float*)d_in[8];
    const float* bf1 = (const float*)d_in[9];
    const float* Wf2 = (const float*)d_in[10];
    const float* bf2 = (const float*)d_in[11];
    float* out = (float*)d_out;

    const int N = N_NODES, E = N_EDGES;
    const int* src = ei;
    const int* dst = ei + E;

    float* ws   = (float*)d_ws;
    float* dinv = ws;                       // N
    float* H    = ws + N;                   // N*128
    float* O    = H + (size_t)N * 128;      // N*128

    const int B = 256;

    // degree -> dinv
    k_deg_init<<<(N + B - 1) / B, B, 0, stream>>>(dinv, N);
    k_deg_acc <<<(E + B - 1) / B, B, 0, stream>>>(dst, dinv, E);
    k_dinv    <<<(N + B - 1) / B, B, 0, stream>>>(dinv, N);

    // ---- layer 1: x(44) -> 128 ----
    k_gemm<D_IN, 128, false><<<(N + 1) / 2, B, 0, stream>>>(x, W1, H, N);
    k_init_out<128><<<(N * 128 + B - 1) / B, B, 0, stream>>>(H, dinv, b1, O, N);
    k_scatter<128><<<((size_t)E * 128 + B - 1) / B, B, 0, stream>>>(H, dinv, src, dst, O, E);

    // ---- layer 2: relu(O)(128) -> 64 ----
    k_gemm<128, 64, true><<<(N + 3) / 4, B, 0, stream>>>(O, W2, H, N);
    k_init_out<64><<<(N * 64 + B - 1) / B, B, 0, stream>>>(H, dinv, b2, O, N);
    k_scatter<64><<<((size_t)E * 64 + B - 1) / B, B, 0, stream>>>(H, dinv, src, dst, O, E);

    // ---- layer 3: relu(O)(64) -> 32 ----
    k_gemm<64, 32, true><<<(N + 7) / 8, B, 0, stream>>>(O, W3, H, N);
    k_init_out<32><<<(N * 32 + B - 1) / B, B, 0, stream>>>(H, dinv, b3, O, N);
    k_scatter<32><<<((size_t)E * 32 + B - 1) / B, B, 0, stream>>>(H, dinv, src, dst, O, E);

    // ---- MLP head ----
    k_mlp<<<(N + B - 1) / B, B, 0, stream>>>(O, Wf1, bf1, Wf2, bf2, out, N);
}

// Round 2
// 658.816 us; speedup vs baseline: 1.4612x; 1.4612x over previous
//
#include <hip/hip_runtime.h>
#include <hip/hip_bf16.h>
#include <math.h>

#define N_NODES 50000
#define N_EDGES 600000
#define D_IN    44

// ---------------- CSR build ----------------

__global__ void k_zero(int* p, int n) {
    int i = blockIdx.x * blockDim.x + threadIdx.x;
    if (i < n) p[i] = 0;
}

__global__ void k_count(const int* __restrict__ dst, int* degc, int e) {
    int i = blockIdx.x * blockDim.x + threadIdx.x;
    if (i < e) atomicAdd(&degc[dst[i]], 1);
}

__global__ void k_dinv(const int* __restrict__ degc, float* dinv, int n) {
    int i = blockIdx.x * blockDim.x + threadIdx.x;
    if (i < n) dinv[i] = rsqrtf(1.0f + (float)degc[i]);   // deg includes self-loop
}

#define SCAN_T 1024
__global__ void k_scan(const int* __restrict__ degc, int* row_ptr, int* cursor, int n) {
    __shared__ int sums[SCAN_T];
    int t = threadIdx.x;
    int C = (n + SCAN_T - 1) / SCAN_T;
    int lo = t * C, hi = min(lo + C, n);
    int s = 0;
    for (int i = lo; i < hi; ++i) s += degc[i];
    sums[t] = s;
    __syncthreads();
    for (int off = 1; off < SCAN_T; off <<= 1) {
        int v = sums[t];
        int u = (t >= off) ? sums[t - off] : 0;
        __syncthreads();
        sums[t] = v + u;
        __syncthreads();
    }
    int run = (t == 0) ? 0 : sums[t - 1];
    for (int i = lo; i < hi; ++i) {
        row_ptr[i] = run;
        cursor[i]  = run;
        run += degc[i];
    }
    if (t == SCAN_T - 1) row_ptr[n] = run;
}

__global__ void k_fill(const int* __restrict__ src, const int* __restrict__ dst,
                       const float* __restrict__ dinv, int* cursor,
                       int* __restrict__ csr_src, float* __restrict__ csr_w, int e) {
    int i = blockIdx.x * blockDim.x + threadIdx.x;
    if (i < e) {
        int s = src[i], d = dst[i];
        int p = atomicAdd(&cursor[d], 1);
        csr_src[p] = s;
        csr_w[p]   = dinv[s] * dinv[d];
    }
}

// ---------------- CSR gather-aggregate ----------------
// out[i,j] = (BIAS_RELU? relu(. + b[j]) : .) of dinv[i]^2*T[i,j] + sum_k w_k*T[src_k,j]
// G threads per node (G = W rounded up to 32/64), lane j handles feature j.

template<int W, int G, bool BIAS_RELU>
__global__ void k_agg(const float* __restrict__ T, const float* __restrict__ dinv,
                      const int* __restrict__ row_ptr, const int* __restrict__ csr_src,
                      const float* __restrict__ csr_w, const float* __restrict__ b,
                      float* __restrict__ O, int n) {
    const int gpb = 256 / G;
    int g = blockIdx.x * gpb + threadIdx.x / G;
    int j = threadIdx.x % G;
    if (g >= n || j >= W) return;
    float di = dinv[g];
    float acc = di * di * T[(size_t)g * W + j];
    int lo = row_ptr[g], hi = row_ptr[g + 1];
    for (int k = lo; k < hi; ++k) {
        int   s = csr_src[k];
        float w = csr_w[k];
        acc += w * T[(size_t)s * W + j];
    }
    if (BIAS_RELU) acc = fmaxf(acc + b[j], 0.0f);
    O[(size_t)g * W + j] = acc;
}

// ---------------- dense GEMM: H = (relu? bias?) X[n,DI] @ W[DI,DO] ----------------

template<int DI, int DO, bool BIAS_RELU>
__global__ void k_gemm(const float* __restrict__ X, const float* __restrict__ W,
                       const float* __restrict__ b, float* __restrict__ H, int n) {
    __shared__ float Ws[DI * DO];
    for (int i = threadIdx.x; i < DI * DO; i += blockDim.x) Ws[i] = W[i];
    __syncthreads();

    const int npb   = 256 / DO;
    const int j     = threadIdx.x % DO;
    const int local = threadIdx.x / DO;

    for (int node = blockIdx.x * npb + local; node < n; node += gridDim.x * npb) {
        const float* xr = X + (size_t)node * DI;
        float acc = 0.0f;
        #pragma unroll
        for (int k = 0; k < DI; ++k) acc += xr[k] * Ws[k * DO + j];
        if (BIAS_RELU) acc = fmaxf(acc + b[j], 0.0f);
        H[(size_t)node * DO + j] = acc;
    }
}

// ---------------- MLP head ----------------

__global__ void k_mlp(const float* __restrict__ O3,
                      const float* __restrict__ Wf1, const float* __restrict__ bf1,
                      const float* __restrict__ Wf2, const float* __restrict__ bf2,
                      float* __restrict__ out, int n) {
    __shared__ float W1s[32 * 16];
    __shared__ float b1s[16];
    __shared__ float W2s[16];
    __shared__ float b2s;
    for (int t = threadIdx.x; t < 32 * 16; t += blockDim.x) W1s[t] = Wf1[t];
    if (threadIdx.x < 16) { b1s[threadIdx.x] = bf1[threadIdx.x]; W2s[threadIdx.x] = Wf2[threadIdx.x]; }
    if (threadIdx.x == 0) b2s = bf2[0];
    __syncthreads();

    for (int node = blockIdx.x * blockDim.x + threadIdx.x; node < n;
         node += gridDim.x * blockDim.x) {
        float h[16];
        #pragma unroll
        for (int j = 0; j < 16; ++j) h[j] = b1s[j];
        const float* xr = O3 + (size_t)node * 32;
        #pragma unroll
        for (int k = 0; k < 32; ++k) {
            float xv = xr[k];   // already relu'd by agg3 (relu idempotent anyway)
            #pragma unroll
            for (int j = 0; j < 16; ++j) h[j] += xv * W1s[k * 16 + j];
        }
        float acc = b2s;
        #pragma unroll
        for (int j = 0; j < 16; ++j) acc += fmaxf(h[j], 0.0f) * W2s[j];
        out[node] = 1.0f / (1.0f + expf(-acc));
    }
}

// ---------------- launch ----------------

extern "C" void kernel_launch(void* const* d_in, const int* in_sizes, int n_in,
                              void* d_out, int out_size, void* d_ws, size_t ws_size,
                              hipStream_t stream) {
    const float* x   = (const float*)d_in[0];
    const int*   ei  = (const int*)d_in[1];
    const float* W1  = (const float*)d_in[2];
    const float* b1  = (const float*)d_in[3];
    const float* W2  = (const float*)d_in[4];
    const float* b2  = (const float*)d_in[5];
    const float* W3  = (const float*)d_in[6];
    const float* b3  = (const float*)d_in[7];
    const float* Wf1 = (const float*)d_in[8];
    const float* bf1 = (const float*)d_in[9];
    const float* Wf2 = (const float*)d_in[10];
    const float* bf2 = (const float*)d_in[11];
    float* out = (float*)d_out;

    const int N = N_NODES, E = N_EDGES;
    const int* src = ei;
    const int* dst = ei + E;

    // workspace layout (all 4-byte elements)
    char* w = (char*)d_ws;
    float* dinv    = (float*)w;                     w += (size_t)N * 4;
    int*   degc    = (int*)w;                       w += (size_t)N * 4;
    int*   row_ptr = (int*)w;                       w += (size_t)(N + 1) * 4;
    int*   cursor  = (int*)w;                       w += (size_t)N * 4;
    int*   csr_src = (int*)w;                       w += (size_t)E * 4;
    float* csr_w   = (float*)w;                     w += (size_t)E * 4;
    float* bufA    = (float*)w;                     w += (size_t)N * 64 * 4;   // max width 64
    float* bufB    = (float*)w;                                                // N*128

    const int B = 256;

    // ---- CSR build ----
    k_zero <<<(N + B - 1) / B, B, 0, stream>>>(degc, N);
    k_count<<<(E + B - 1) / B, B, 0, stream>>>(dst, degc, E);
    k_dinv <<<(N + B - 1) / B, B, 0, stream>>>(degc, dinv, N);
    k_scan <<<1, SCAN_T, 0, stream>>>(degc, row_ptr, cursor, N);
    k_fill <<<(E + B - 1) / B, B, 0, stream>>>(src, dst, dinv, cursor, csr_src, csr_w, E);

    // ---- layer 1: aggregate x at 44 dims, then GEMM 44->128 (+b1, relu) ----
    k_agg<44, 64, false><<<(N * 64 + B - 1) / B, B, 0, stream>>>(
        x, dinv, row_ptr, csr_src, csr_w, nullptr, bufA, N);
    k_gemm<44, 128, true><<<2560, B, 0, stream>>>(bufA, W1, b1, bufB, N);

    // ---- layer 2: GEMM 128->64, aggregate at 64 (+b2, relu) ----
    k_gemm<128, 64, false><<<2560, B, 0, stream>>>(bufB, W2, nullptr, bufA, N);
    k_agg<64, 64, true><<<(N * 64 + B - 1) / B, B, 0, stream>>>(
        bufA, dinv, row_ptr, csr_src, csr_w, b2, bufB, N);

    // ---- layer 3: GEMM 64->32, aggregate at 32 (+b3, relu) ----
    k_gemm<64, 32, false><<<2560, B, 0, stream>>>(bufB, W3, nullptr, bufA, N);
    k_agg<32, 32, true><<<(N * 32 + B - 1) / B, B, 0, stream>>>(
        bufA, dinv, row_ptr, csr_src, csr_w, b3, bufB, N);

    // ---- MLP head ----
    k_mlp<<<(N + B - 1) / B, B, 0, stream>>>(bufB, Wf1, bf1, Wf2, bf2, out, N);
}

// Round 3
// 468.627 us; speedup vs baseline: 2.0543x; 1.4058x over previous
//
#include <hip/hip_runtime.h>
#include <hip/hip_bf16.h>
#include <math.h>

#define N_NODES 50000
#define N_EDGES 600000
#define D_IN    44

// ---------------- CSR build ----------------

__global__ void k_zero(int* p, int n) {
    int i = blockIdx.x * blockDim.x + threadIdx.x;
    if (i < n) p[i] = 0;
}

__global__ void k_count(const int* __restrict__ dst, int* degc, int e) {
    int i = blockIdx.x * blockDim.x + threadIdx.x;
    if (i < e) atomicAdd(&degc[dst[i]], 1);
}

#define SCAN_T 1024
__global__ void k_scan(const int* __restrict__ degc, int* row_ptr, int* cursor,
                       float* dinv, int n) {
    __shared__ int sums[SCAN_T];
    int t = threadIdx.x;
    int C = (n + SCAN_T - 1) / SCAN_T;
    int lo = t * C, hi = min(lo + C, n);
    int s = 0;
    for (int i = lo; i < hi; ++i) s += degc[i];
    sums[t] = s;
    __syncthreads();
    for (int off = 1; off < SCAN_T; off <<= 1) {
        int v = sums[t];
        int u = (t >= off) ? sums[t - off] : 0;
        __syncthreads();
        sums[t] = v + u;
        __syncthreads();
    }
    int run = (t == 0) ? 0 : sums[t - 1];
    for (int i = lo; i < hi; ++i) {
        row_ptr[i] = run;
        cursor[i]  = run;
        dinv[i]    = rsqrtf(1.0f + (float)degc[i]);   // deg includes self-loop
        run += degc[i];
    }
    if (t == SCAN_T - 1) row_ptr[n] = run;
}

__global__ void k_fill(const int* __restrict__ src, const int* __restrict__ dst,
                       const float* __restrict__ dinv, int* cursor,
                       int* __restrict__ csr_src, float* __restrict__ csr_w, int e) {
    int i = blockIdx.x * blockDim.x + threadIdx.x;
    if (i < e) {
        int s = src[i], d = dst[i];
        int p = atomicAdd(&cursor[d], 1);
        csr_src[p] = s;
        csr_w[p]   = dinv[s] * dinv[d];
    }
}

// ---------------- CSR gather-aggregate, float4 lanes ----------------
// G lanes per node; lane j handles features [4j, 4j+4). Software-pipelined
// index prefetch to hide the dependent csr_src -> row-gather latency.

template<int W, int G, bool BIAS_RELU>
__global__ void k_agg4(const float* __restrict__ T, const float* __restrict__ dinv,
                       const int* __restrict__ row_ptr, const int* __restrict__ csr_src,
                       const float* __restrict__ csr_w, const float* __restrict__ b,
                       float* __restrict__ O, int n) {
    constexpr int W4 = W / 4;
    const int gpb = 256 / G;
    int g = blockIdx.x * gpb + threadIdx.x / G;
    int j = threadIdx.x % G;
    if (g >= n || j >= W4) return;

    const float4* T4 = (const float4*)T;
    float di = dinv[g];
    float  sw = di * di;
    float4 t  = T4[(size_t)g * W4 + j];
    float4 acc = make_float4(sw * t.x, sw * t.y, sw * t.z, sw * t.w);

    int lo = row_ptr[g], hi = row_ptr[g + 1];
    int   s_n = 0; float w_n = 0.0f;
    if (lo < hi) { s_n = csr_src[lo]; w_n = csr_w[lo]; }
    for (int k = lo; k < hi; ++k) {
        int s_c = s_n; float w_c = w_n;
        if (k + 1 < hi) { s_n = csr_src[k + 1]; w_n = csr_w[k + 1]; }
        float4 tv = T4[(size_t)s_c * W4 + j];
        acc.x += w_c * tv.x; acc.y += w_c * tv.y;
        acc.z += w_c * tv.z; acc.w += w_c * tv.w;
    }
    if (BIAS_RELU) {
        float4 bv = ((const float4*)b)[j];
        acc.x = fmaxf(acc.x + bv.x, 0.0f);
        acc.y = fmaxf(acc.y + bv.y, 0.0f);
        acc.z = fmaxf(acc.z + bv.z, 0.0f);
        acc.w = fmaxf(acc.w + bv.w, 0.0f);
    }
    ((float4*)O)[(size_t)g * W4 + j] = acc;
}

// ---------------- register-blocked GEMM ----------------
// One thread = one node x CT columns. W column-tile in LDS (broadcast reads),
// x row as float4, CT independent accumulator chains.

template<int DI, int DO, int CT, bool BIAS_RELU>
__global__ void k_gemm(const float* __restrict__ X, const float* __restrict__ W,
                       const float* __restrict__ b, float* __restrict__ H, int n) {
    __shared__ float Ws[DI * CT];
    const int ct0 = blockIdx.y * CT;
    for (int i = threadIdx.x; i < DI * CT; i += blockDim.x) {
        int k = i / CT, c = i % CT;
        Ws[i] = W[k * DO + ct0 + c];
    }
    __syncthreads();

    int node = blockIdx.x * blockDim.x + threadIdx.x;
    if (node >= n) return;

    float acc[CT];
    #pragma unroll
    for (int c = 0; c < CT; ++c) acc[c] = BIAS_RELU ? b[ct0 + c] : 0.0f;

    const float4* xr = (const float4*)(X + (size_t)node * DI);
    #pragma unroll
    for (int k0 = 0; k0 < DI / 4; ++k0) {
        float4 xv = xr[k0];
        #pragma unroll
        for (int c = 0; c < CT; ++c) acc[c] += xv.x * Ws[(k0 * 4 + 0) * CT + c];
        #pragma unroll
        for (int c = 0; c < CT; ++c) acc[c] += xv.y * Ws[(k0 * 4 + 1) * CT + c];
        #pragma unroll
        for (int c = 0; c < CT; ++c) acc[c] += xv.z * Ws[(k0 * 4 + 2) * CT + c];
        #pragma unroll
        for (int c = 0; c < CT; ++c) acc[c] += xv.w * Ws[(k0 * 4 + 3) * CT + c];
    }

    float* hr = H + (size_t)node * DO + ct0;
    #pragma unroll
    for (int c4 = 0; c4 < CT / 4; ++c4) {
        float4 v;
        v.x = acc[c4 * 4 + 0]; v.y = acc[c4 * 4 + 1];
        v.z = acc[c4 * 4 + 2]; v.w = acc[c4 * 4 + 3];
        if (BIAS_RELU) {
            v.x = fmaxf(v.x, 0.0f); v.y = fmaxf(v.y, 0.0f);
            v.z = fmaxf(v.z, 0.0f); v.w = fmaxf(v.w, 0.0f);
        }
        ((float4*)hr)[c4] = v;
    }
}

// ---------------- MLP head ----------------

__global__ void k_mlp(const float* __restrict__ O3,
                      const float* __restrict__ Wf1, const float* __restrict__ bf1,
                      const float* __restrict__ Wf2, const float* __restrict__ bf2,
                      float* __restrict__ out, int n) {
    __shared__ float W1s[32 * 16];
    __shared__ float b1s[16];
    __shared__ float W2s[16];
    __shared__ float b2s;
    for (int t = threadIdx.x; t < 32 * 16; t += blockDim.x) W1s[t] = Wf1[t];
    if (threadIdx.x < 16) { b1s[threadIdx.x] = bf1[threadIdx.x]; W2s[threadIdx.x] = Wf2[threadIdx.x]; }
    if (threadIdx.x == 0) b2s = bf2[0];
    __syncthreads();

    for (int node = blockIdx.x * blockDim.x + threadIdx.x; node < n;
         node += gridDim.x * blockDim.x) {
        float h[16];
        #pragma unroll
        for (int j = 0; j < 16; ++j) h[j] = b1s[j];
        const float* xr = O3 + (size_t)node * 32;
        #pragma unroll
        for (int k = 0; k < 32; ++k) {
            float xv = xr[k];
            #pragma unroll
            for (int j = 0; j < 16; ++j) h[j] += xv * W1s[k * 16 + j];
        }
        float acc = b2s;
        #pragma unroll
        for (int j = 0; j < 16; ++j) acc += fmaxf(h[j], 0.0f) * W2s[j];
        out[node] = 1.0f / (1.0f + expf(-acc));
    }
}

// ---------------- launch ----------------

extern "C" void kernel_launch(void* const* d_in, const int* in_sizes, int n_in,
                              void* d_out, int out_size, void* d_ws, size_t ws_size,
                              hipStream_t stream) {
    const float* x   = (const float*)d_in[0];
    const int*   ei  = (const int*)d_in[1];
    const float* W1  = (const float*)d_in[2];
    const float* b1  = (const float*)d_in[3];
    const float* W2  = (const float*)d_in[4];
    const float* b2  = (const float*)d_in[5];
    const float* W3  = (const float*)d_in[6];
    const float* b3  = (const float*)d_in[7];
    const float* Wf1 = (const float*)d_in[8];
    const float* bf1 = (const float*)d_in[9];
    const float* Wf2 = (const float*)d_in[10];
    const float* bf2 = (const float*)d_in[11];
    float* out = (float*)d_out;

    const int N = N_NODES, E = N_EDGES;
    const int* src = ei;
    const int* dst = ei + E;

    char* w = (char*)d_ws;
    float* dinv    = (float*)w;                     w += (size_t)N * 4;
    int*   degc    = (int*)w;                       w += (size_t)N * 4;
    int*   row_ptr = (int*)w;                       w += (size_t)(N + 4) * 4;
    int*   cursor  = (int*)w;                       w += (size_t)N * 4;
    int*   csr_src = (int*)w;                       w += (size_t)E * 4;
    float* csr_w   = (float*)w;                     w += (size_t)E * 4;
    float* bufA    = (float*)w;                     w += (size_t)N * 64 * 4;
    float* bufB    = (float*)w;                                              // N*128

    const int B = 256;
    const int NB = (N + B - 1) / B;   // 196

    // ---- CSR build ----
    k_zero <<<(N + B - 1) / B, B, 0, stream>>>(degc, N);
    k_count<<<(E + B - 1) / B, B, 0, stream>>>(dst, degc, E);
    k_scan <<<1, SCAN_T, 0, stream>>>(degc, row_ptr, cursor, dinv, N);
    k_fill <<<(E + B - 1) / B, B, 0, stream>>>(src, dst, dinv, cursor, csr_src, csr_w, E);

    // ---- layer 1: aggregate x at 44 dims, then GEMM 44->128 (+b1, relu) ----
    k_agg4<44, 16, false><<<(N * 16 + B - 1) / B, B, 0, stream>>>(
        x, dinv, row_ptr, csr_src, csr_w, nullptr, bufA, N);
    k_gemm<44, 128, 32, true><<<dim3(NB, 4), B, 0, stream>>>(bufA, W1, b1, bufB, N);

    // ---- layer 2: GEMM 128->64, aggregate at 64 (+b2, relu) ----
    k_gemm<128, 64, 32, false><<<dim3(NB, 2), B, 0, stream>>>(bufB, W2, nullptr, bufA, N);
    k_agg4<64, 16, true><<<(N * 16 + B - 1) / B, B, 0, stream>>>(
        bufA, dinv, row_ptr, csr_src, csr_w, b2, bufB, N);

    // ---- layer 3: GEMM 64->32, aggregate at 32 (+b3, relu) ----
    k_gemm<64, 32, 16, false><<<dim3(NB, 2), B, 0, stream>>>(bufB, W3, nullptr, bufA, N);
    k_agg4<32, 8, true><<<(N * 8 + B - 1) / B, B, 0, stream>>>(
        bufA, dinv, row_ptr, csr_src, csr_w, b3, bufB, N);

    // ---- MLP head ----
    k_mlp<<<(N + B - 1) / B, B, 0, stream>>>(bufB, Wf1, bf1, Wf2, bf2, out, N);
}

// Round 4
// 360.525 us; speedup vs baseline: 2.6703x; 1.2998x over previous
//
#include <hip/hip_runtime.h>
#include <hip/hip_bf16.h>
#include <math.h>

#define N_NODES 50000
#define N_EDGES 600000
#define D_IN    44

// ---------------- CSR build ----------------

__global__ void k_zero(int* p, int n) {
    int i = blockIdx.x * blockDim.x + threadIdx.x;
    if (i < n) p[i] = 0;
}

__global__ void k_count(const int* __restrict__ dst, int* degc, int e) {
    int i = blockIdx.x * blockDim.x + threadIdx.x;
    if (i < e) atomicAdd(&degc[dst[i]], 1);
}

// phase 1: per-block (256-chunk) sums of degc
__global__ void k_blocksum(const int* __restrict__ degc, int* __restrict__ bsum, int n) {
    int i = blockIdx.x * 256 + threadIdx.x;
    int v = (i < n) ? degc[i] : 0;
    #pragma unroll
    for (int off = 32; off > 0; off >>= 1) v += __shfl_down(v, off, 64);
    __shared__ int ws[4];
    if ((threadIdx.x & 63) == 0) ws[threadIdx.x >> 6] = v;
    __syncthreads();
    if (threadIdx.x == 0) bsum[blockIdx.x] = ws[0] + ws[1] + ws[2] + ws[3];
}

// phase 2: exclusive scan of block sums (nb <= 256), single block
__global__ void k_scanbsum(int* bsum, int nb) {
    __shared__ int s[256];
    int t = threadIdx.x;
    int v = (t < nb) ? bsum[t] : 0;
    s[t] = v;
    __syncthreads();
    #pragma unroll
    for (int off = 1; off < 256; off <<= 1) {
        int u = (t >= off) ? s[t - off] : 0;
        __syncthreads();
        s[t] += u;
        __syncthreads();
    }
    if (t < nb) bsum[t] = (t == 0) ? 0 : s[t - 1];
}

// phase 3: per-block scan + global offset -> row_ptr, cursor, dinv
__global__ void k_rowptr(const int* __restrict__ degc, const int* __restrict__ bsum,
                         int* __restrict__ row_ptr, int* __restrict__ cursor,
                         float* __restrict__ dinv, int n) {
    __shared__ int s[256];
    int i = blockIdx.x * 256 + threadIdx.x;
    int t = threadIdx.x;
    int d = (i < n) ? degc[i] : 0;
    s[t] = d;
    __syncthreads();
    #pragma unroll
    for (int off = 1; off < 256; off <<= 1) {
        int u = (t >= off) ? s[t - off] : 0;
        __syncthreads();
        s[t] += u;
        __syncthreads();
    }
    int ex = s[t] - d + bsum[blockIdx.x];
    if (i < n) {
        row_ptr[i] = ex;
        cursor[i]  = ex;
        dinv[i]    = rsqrtf(1.0f + (float)d);   // deg includes self-loop
        if (i == n - 1) row_ptr[n] = ex + d;
    }
}

__global__ void k_fill(const int* __restrict__ src, const int* __restrict__ dst,
                       const float* __restrict__ dinv, int* cursor,
                       int* __restrict__ csr_src, float* __restrict__ csr_w, int e) {
    int i = blockIdx.x * blockDim.x + threadIdx.x;
    if (i < e) {
        int s = src[i], d = dst[i];
        int p = atomicAdd(&cursor[d], 1);
        csr_src[p] = s;
        csr_w[p]   = dinv[s] * dinv[d];
    }
}

// ---------------- CSR gather-aggregate, float4 lanes ----------------

template<int W, int G, bool BIAS_RELU>
__global__ void k_agg4(const float* __restrict__ T, const float* __restrict__ dinv,
                       const int* __restrict__ row_ptr, const int* __restrict__ csr_src,
                       const float* __restrict__ csr_w, const float* __restrict__ b,
                       float* __restrict__ O, int n) {
    constexpr int W4 = W / 4;
    const int gpb = 256 / G;
    int g = blockIdx.x * gpb + threadIdx.x / G;
    int j = threadIdx.x % G;
    if (g >= n || j >= W4) return;

    const float4* T4 = (const float4*)T;
    float di = dinv[g];
    float  sw = di * di;
    float4 t  = T4[(size_t)g * W4 + j];
    float4 acc = make_float4(sw * t.x, sw * t.y, sw * t.z, sw * t.w);

    int lo = row_ptr[g], hi = row_ptr[g + 1];
    int   s_n = 0; float w_n = 0.0f;
    if (lo < hi) { s_n = csr_src[lo]; w_n = csr_w[lo]; }
    for (int k = lo; k < hi; ++k) {
        int s_c = s_n; float w_c = w_n;
        if (k + 1 < hi) { s_n = csr_src[k + 1]; w_n = csr_w[k + 1]; }
        float4 tv = T4[(size_t)s_c * W4 + j];
        acc.x += w_c * tv.x; acc.y += w_c * tv.y;
        acc.z += w_c * tv.z; acc.w += w_c * tv.w;
    }
    if (BIAS_RELU) {
        float4 bv = ((const float4*)b)[j];
        acc.x = fmaxf(acc.x + bv.x, 0.0f);
        acc.y = fmaxf(acc.y + bv.y, 0.0f);
        acc.z = fmaxf(acc.z + bv.z, 0.0f);
        acc.w = fmaxf(acc.w + bv.w, 0.0f);
    }
    ((float4*)O)[(size_t)g * W4 + j] = acc;
}

// ---------------- register-blocked GEMM ----------------

template<int DI, int DO, int CT, bool BIAS_RELU>
__global__ void k_gemm(const float* __restrict__ X, const float* __restrict__ W,
                       const float* __restrict__ b, float* __restrict__ H, int n) {
    __shared__ float Ws[DI * CT];
    const int ct0 = blockIdx.y * CT;
    for (int i = threadIdx.x; i < DI * CT; i += blockDim.x) {
        int k = i / CT, c = i % CT;
        Ws[i] = W[k * DO + ct0 + c];
    }
    __syncthreads();

    int node = blockIdx.x * blockDim.x + threadIdx.x;
    if (node >= n) return;

    float acc[CT];
    #pragma unroll
    for (int c = 0; c < CT; ++c) acc[c] = BIAS_RELU ? b[ct0 + c] : 0.0f;

    const float4* xr = (const float4*)(X + (size_t)node * DI);
    #pragma unroll
    for (int k0 = 0; k0 < DI / 4; ++k0) {
        float4 xv = xr[k0];
        #pragma unroll
        for (int c = 0; c < CT; ++c) acc[c] += xv.x * Ws[(k0 * 4 + 0) * CT + c];
        #pragma unroll
        for (int c = 0; c < CT; ++c) acc[c] += xv.y * Ws[(k0 * 4 + 1) * CT + c];
        #pragma unroll
        for (int c = 0; c < CT; ++c) acc[c] += xv.z * Ws[(k0 * 4 + 2) * CT + c];
        #pragma unroll
        for (int c = 0; c < CT; ++c) acc[c] += xv.w * Ws[(k0 * 4 + 3) * CT + c];
    }

    float* hr = H + (size_t)node * DO + ct0;
    #pragma unroll
    for (int c4 = 0; c4 < CT / 4; ++c4) {
        float4 v;
        v.x = acc[c4 * 4 + 0]; v.y = acc[c4 * 4 + 1];
        v.z = acc[c4 * 4 + 2]; v.w = acc[c4 * 4 + 3];
        if (BIAS_RELU) {
            v.x = fmaxf(v.x, 0.0f); v.y = fmaxf(v.y, 0.0f);
            v.z = fmaxf(v.z, 0.0f); v.w = fmaxf(v.w, 0.0f);
        }
        ((float4*)hr)[c4] = v;
    }
}

// ---------------- MLP head ----------------

__global__ void k_mlp(const float* __restrict__ O3,
                      const float* __restrict__ Wf1, const float* __restrict__ bf1,
                      const float* __restrict__ Wf2, const float* __restrict__ bf2,
                      float* __restrict__ out, int n) {
    __shared__ float W1s[32 * 16];
    __shared__ float b1s[16];
    __shared__ float W2s[16];
    __shared__ float b2s;
    for (int t = threadIdx.x; t < 32 * 16; t += blockDim.x) W1s[t] = Wf1[t];
    if (threadIdx.x < 16) { b1s[threadIdx.x] = bf1[threadIdx.x]; W2s[threadIdx.x] = Wf2[threadIdx.x]; }
    if (threadIdx.x == 0) b2s = bf2[0];
    __syncthreads();

    for (int node = blockIdx.x * blockDim.x + threadIdx.x; node < n;
         node += gridDim.x * blockDim.x) {
        float h[16];
        #pragma unroll
        for (int j = 0; j < 16; ++j) h[j] = b1s[j];
        const float* xr = O3 + (size_t)node * 32;
        #pragma unroll
        for (int k = 0; k < 32; ++k) {
            float xv = xr[k];
            #pragma unroll
            for (int j = 0; j < 16; ++j) h[j] += xv * W1s[k * 16 + j];
        }
        float acc = b2s;
        #pragma unroll
        for (int j = 0; j < 16; ++j) acc += fmaxf(h[j], 0.0f) * W2s[j];
        out[node] = 1.0f / (1.0f + expf(-acc));
    }
}

// ---------------- launch ----------------

extern "C" void kernel_launch(void* const* d_in, const int* in_sizes, int n_in,
                              void* d_out, int out_size, void* d_ws, size_t ws_size,
                              hipStream_t stream) {
    const float* x   = (const float*)d_in[0];
    const int*   ei  = (const int*)d_in[1];
    const float* W1  = (const float*)d_in[2];
    const float* b1  = (const float*)d_in[3];
    const float* W2  = (const float*)d_in[4];
    const float* b2  = (const float*)d_in[5];
    const float* W3  = (const float*)d_in[6];
    const float* b3  = (const float*)d_in[7];
    const float* Wf1 = (const float*)d_in[8];
    const float* bf1 = (const float*)d_in[9];
    const float* Wf2 = (const float*)d_in[10];
    const float* bf2 = (const float*)d_in[11];
    float* out = (float*)d_out;

    const int N = N_NODES, E = N_EDGES;
    const int* src = ei;
    const int* dst = ei + E;

    char* w = (char*)d_ws;
    float* dinv    = (float*)w;                     w += (size_t)N * 4;
    int*   degc    = (int*)w;                       w += (size_t)N * 4;
    int*   row_ptr = (int*)w;                       w += (size_t)(N + 4) * 4;
    int*   cursor  = (int*)w;                       w += (size_t)N * 4;
    int*   bsum    = (int*)w;                       w += (size_t)256 * 4;
    int*   csr_src = (int*)w;                       w += (size_t)E * 4;
    float* csr_w   = (float*)w;                     w += (size_t)E * 4;
    float* bufA    = (float*)w;                     w += (size_t)N * 64 * 4;
    float* bufB    = (float*)w;                                              // N*128

    const int B = 256;
    const int NB = (N + B - 1) / B;   // 196

    // ---- CSR build (parallel 3-phase scan) ----
    k_zero     <<<NB, B, 0, stream>>>(degc, N);
    k_count    <<<(E + B - 1) / B, B, 0, stream>>>(dst, degc, E);
    k_blocksum <<<NB, B, 0, stream>>>(degc, bsum, N);
    k_scanbsum <<<1, B, 0, stream>>>(bsum, NB);
    k_rowptr   <<<NB, B, 0, stream>>>(degc, bsum, row_ptr, cursor, dinv, N);
    k_fill     <<<(E + B - 1) / B, B, 0, stream>>>(src, dst, dinv, cursor, csr_src, csr_w, E);

    // ---- layer 1: aggregate x at 44 dims, then GEMM 44->128 (+b1, relu) ----
    k_agg4<44, 16, false><<<(N * 16 + B - 1) / B, B, 0, stream>>>(
        x, dinv, row_ptr, csr_src, csr_w, nullptr, bufA, N);
    k_gemm<44, 128, 32, true><<<dim3(NB, 4), B, 0, stream>>>(bufA, W1, b1, bufB, N);

    // ---- layer 2: GEMM 128->64, aggregate at 64 (+b2, relu) ----
    k_gemm<128, 64, 32, false><<<dim3(NB, 2), B, 0, stream>>>(bufB, W2, nullptr, bufA, N);
    k_agg4<64, 16, true><<<(N * 16 + B - 1) / B, B, 0, stream>>>(
        bufA, dinv, row_ptr, csr_src, csr_w, b2, bufB, N);

    // ---- layer 3: GEMM 64->32, aggregate at 32 (+b3, relu) ----
    k_gemm<64, 32, 16, false><<<dim3(NB, 2), B, 0, stream>>>(bufB, W3, nullptr, bufA, N);
    k_agg4<32, 8, true><<<(N * 8 + B - 1) / B, B, 0, stream>>>(
        bufA, dinv, row_ptr, csr_src, csr_w, b3, bufB, N);

    // ---- MLP head ----
    k_mlp<<<NB, B, 0, stream>>>(bufB, Wf1, bf1, Wf2, bf2, out, N);
}